// Round 8
// baseline (121.627 us; speedup 1.0000x reference)
//
#include <hip/hip_runtime.h>

#define EPS_ 1.1920928955078125e-07f
#define SCALE_ 0.17677669529663687f   // 1/sqrt(32)

typedef __attribute__((ext_vector_type(8))) short s8b;     // 8 bf16 (16B)
typedef __attribute__((ext_vector_type(4))) float f32x4;   // MFMA acc

static __device__ __forceinline__ unsigned short f2bf(float f) {
  unsigned int u = __float_as_uint(f);
  unsigned int r = (u + 0x7fffu + ((u >> 16) & 1u)) >> 16;   // RNE
  return (unsigned short)r;
}
static __device__ __forceinline__ float b2fs(short h) {
  return __uint_as_float(((unsigned int)(unsigned short)h) << 16);
}
static __device__ __forceinline__ int S_(int c) {        // NATTEN window start (cell grid)
  return (c < 3) ? 0 : ((c > 28) ? 25 : (c - 3));
}
// 16B of bf16 from a 4B-aligned pointer (4 dword loads)
static __device__ __forceinline__ s8b ld8h(const unsigned short* p) {
  const unsigned int* u = (const unsigned int*)p;
  union { unsigned int u4[4]; s8b v; } r;
  r.u4[0] = u[0]; r.u4[1] = u[1]; r.u4[2] = u[2]; r.u4[3] = u[3];
  return r.v;
}

// ---------------------------------------------------------------------------
// prep (grid 985):
//  [0,256)   q fp32 NCHW -> bf16 NHWC padded qb [130][130][128]
//  [256,265) zero qb halo border
//  [265,281) k-side: rms + kproj MFMA -> kpb [1024][128] bf16 NHWC (64 px/blk)
//  [281,345) v fp32 -> vt bf16 [128][1024] (same layout, cast only)
//  [345,985) weight packs: wb [9][4][128oc][32ic], wnq [128][128]
// ---------------------------------------------------------------------------
__global__ __launch_bounds__(256) void prep_k(
    const float* __restrict__ q_in, const float* __restrict__ k_in,
    const float* __restrict__ v_in, const float* __restrict__ conv_w,
    const float* __restrict__ normq_w, const float* __restrict__ normk_w,
    const float* __restrict__ qproj_w, const float* __restrict__ kproj_w,
    const float* __restrict__ kbias,
    unsigned short* __restrict__ qb, unsigned short* __restrict__ kpb,
    unsigned short* __restrict__ vt, unsigned short* __restrict__ wb,
    unsigned short* __restrict__ wnq) {
  __shared__ __align__(16) char smem[53504];
  unsigned short* t_l = (unsigned short*)smem;             // [64][136]
  unsigned short* x_l = (unsigned short*)smem;             // [64][136] (k-proj)
  unsigned short* wnk_l = (unsigned short*)(smem + 17408); // [128][136]
  float* red_l = (float*)(smem + 52224);                   // [256]
  float* rs_l  = (float*)(smem + 53248);                   // [64]
  const int b = blockIdx.x, tid = threadIdx.x;
  const int w = tid >> 6, lane = tid & 63;
  const int lm = lane & 15, kg = lane >> 4;

  if (b < 256) {
    const int px0 = b * 64;
    for (int i = tid; i < 2048; i += 256) {
      int c = i >> 4, f = i & 15;
      float4 v = *(const float4*)&q_in[c * 16384 + px0 + f * 4];
      t_l[(f * 4 + 0) * 136 + c] = f2bf(v.x);
      t_l[(f * 4 + 1) * 136 + c] = f2bf(v.y);
      t_l[(f * 4 + 2) * 136 + c] = f2bf(v.z);
      t_l[(f * 4 + 3) * 136 + c] = f2bf(v.w);
    }
    __syncthreads();
    for (int i = tid; i < 1024; i += 256) {
      int p = i >> 4, s = i & 15;
      int px = px0 + p;
      int opx = px + 2 * (px >> 7) + 131;   // (y+1)*130 + (x+1)
      *(s8b*)&qb[opx * 128 + s * 8] = *(const s8b*)&t_l[p * 136 + s * 8];
    }
  } else if (b < 265) {
    int gid = (b - 256) * 256 + tid;   // 2304 threads
    s8b z = {0, 0, 0, 0, 0, 0, 0, 0};
    for (int j = gid; j < 2080; j += 2304) {
      *(s8b*)&qb[j * 8] = z;
      *(s8b*)&qb[129 * 130 * 128 + j * 8] = z;
    }
    for (int j = gid; j < 2048; j += 2304) {
      int r = (j >> 4) + 1, s = j & 15;
      *(s8b*)&qb[(r * 130) * 128 + s * 8] = z;
      *(s8b*)&qb[(r * 130 + 129) * 128 + s * 8] = z;
    }
  } else if (b < 281) {
    // ------- k-side rms + proj, 64 px -------
    const int px0 = (b - 265) * 64;
    for (int i = tid; i < 2048; i += 256) {
      int c = i >> 4, f = i & 15;
      float4 v = *(const float4*)&k_in[c * 1024 + px0 + f * 4];
      x_l[(f * 4 + 0) * 136 + c] = f2bf(v.x);
      x_l[(f * 4 + 1) * 136 + c] = f2bf(v.y);
      x_l[(f * 4 + 2) * 136 + c] = f2bf(v.z);
      x_l[(f * 4 + 3) * 136 + c] = f2bf(v.w);
    }
    for (int i = tid; i < 16384; i += 256) {
      int o = i >> 7, c = i & 127;
      wnk_l[o * 136 + c] = f2bf(kproj_w[i] * normk_w[c]);
    }
    __syncthreads();
    {
      int px = tid >> 2, t4 = tid & 3;
      float ssum = 0.f;
#pragma unroll
      for (int j = 0; j < 4; j++) {
        s8b v = *(const s8b*)&x_l[px * 136 + t4 * 32 + j * 8];
#pragma unroll
        for (int e = 0; e < 8; e++) { float f = b2fs(v[e]); ssum += f * f; }
      }
      red_l[px * 4 + t4] = ssum;
    }
    __syncthreads();
    if (tid < 64)
      rs_l[tid] = rsqrtf((red_l[4 * tid] + red_l[4 * tid + 1] + red_l[4 * tid + 2] +
                          red_l[4 * tid + 3]) * (1.f / 128.f) + EPS_);
    __syncthreads();
    f32x4 acc[2][4];
#pragma unroll
    for (int a = 0; a < 2; a++)
#pragma unroll
      for (int n = 0; n < 4; n++) acc[a][n] = (f32x4){0.f, 0.f, 0.f, 0.f};
#pragma unroll
    for (int kc = 0; kc < 4; kc++) {
      s8b a0 = *(const s8b*)&wnk_l[(2 * w * 16 + lm) * 136 + kc * 32 + kg * 8];
      s8b a1 = *(const s8b*)&wnk_l[((2 * w + 1) * 16 + lm) * 136 + kc * 32 + kg * 8];
#pragma unroll
      for (int nt = 0; nt < 4; nt++) {
        s8b bf = *(const s8b*)&x_l[(nt * 16 + lm) * 136 + kc * 32 + kg * 8];
        acc[0][nt] = __builtin_amdgcn_mfma_f32_16x16x32_bf16(a0, bf, acc[0][nt], 0, 0, 0);
        acc[1][nt] = __builtin_amdgcn_mfma_f32_16x16x32_bf16(a1, bf, acc[1][nt], 0, 0, 0);
      }
    }
    __syncthreads();
#pragma unroll
    for (int mi = 0; mi < 2; mi++)
#pragma unroll
      for (int nt = 0; nt < 4; nt++)
#pragma unroll
        for (int r = 0; r < 4; r++) {
          int px = nt * 16 + lm, c = (2 * w + mi) * 16 + kg * 4 + r;
          x_l[px * 136 + c] = f2bf(kbias[c] + rs_l[px] * acc[mi][nt][r]);
        }
    __syncthreads();
    for (int i = tid; i < 1024; i += 256) {
      int px = i >> 4, s = i & 15;
      *(s8b*)&kpb[(px0 + px) * 128 + s * 8] = *(const s8b*)&x_l[px * 136 + s * 8];
    }
  } else if (b < 345) {
    // ------- vt: bf16 cast of v (layout unchanged) -------
    int base = (b - 281) * 2048 + tid * 8;
    float4 v0 = *(const float4*)&v_in[base];
    float4 v1 = *(const float4*)&v_in[base + 4];
    s8b o;
    o[0] = (short)f2bf(v0.x); o[1] = (short)f2bf(v0.y);
    o[2] = (short)f2bf(v0.z); o[3] = (short)f2bf(v0.w);
    o[4] = (short)f2bf(v1.x); o[5] = (short)f2bf(v1.y);
    o[6] = (short)f2bf(v1.z); o[7] = (short)f2bf(v1.w);
    *(s8b*)&vt[base] = o;
  } else {
    int idx = (b - 345) * 256 + tid;   // < 163840
    if (idx < 147456) {
      int i32 = idx & 31, r = idx >> 5;
      int oc = r & 127, r2 = r >> 7;
      int kc = r2 & 3, t = r2 >> 2;
      wb[idx] = f2bf(conv_w[oc * 1152 + (kc * 32 + i32) * 9 + t]);
    } else {
      int j = idx - 147456;
      wnq[j] = f2bf(qproj_w[j] * normq_w[j & 127]);
    }
  }
}

// ---------------------------------------------------------------------------
// fused (grid 512, 256 thr = 4 waves): per 8y x 4x output tile.
// Conv halo staged in LDS; ALL other operands (conv/proj weights, K, V) read
// directly from L2-hot global. ~19.6 KB LDS -> 2-4 blocks/CU for cross-block
// phase overlap.
// LDS (19584B): R0 @0 (18432): in_l[60][136] -> qc_l[32][136] -> a_l[4][32][72]
//               -> o_l[128][36] f32 ; red @18432 [256] ; rs @19456 [32]
// ---------------------------------------------------------------------------
__global__ __launch_bounds__(256, 4) void fused_k(
    const unsigned short* __restrict__ qb, const unsigned short* __restrict__ kpb,
    const unsigned short* __restrict__ vt, const unsigned short* __restrict__ wb,
    const unsigned short* __restrict__ wnq, const float* __restrict__ qbias,
    float* __restrict__ out) {
  __shared__ __align__(16) char smem[19584];
  unsigned short* in_l = (unsigned short*)smem;
  unsigned short* qc_l = (unsigned short*)smem;
  unsigned short* a_l  = (unsigned short*)smem;
  float* o_l   = (float*)smem;
  float* red_l = (float*)(smem + 18432);
  float* rs_l  = (float*)(smem + 19456);

  const int tid = threadIdx.x;                 // 0..255
  const int TY = blockIdx.x >> 5, TX = blockIdx.x & 31;
  const int Y0 = TY * 8, X0 = TX * 4;
  const int w = tid >> 6, lane = tid & 63;
  const int lm = lane & 15, kg = lane >> 4;
  const int mg = w & 1, ng = w >> 1;           // conv/proj: 4 m-tiles, 1 n-tile

  const int sy0 = S_(2 * TY), sy1 = S_(2 * TY + 1);
  const int sx  = S_(TX);
  const int kyb = min(sy0, 24);
  const int kxb = sx & ~1;                     // even -> 4B-aligned V rows
  const int oy0 = sy0 - kyb, oy1 = sy1 - kyb;
  const int ox  = sx - kxb;

  // ---- stage conv halo [60][136] from padded qb ----
  for (int i = tid; i < 960; i += 256) {
    int s = i & 15, r = i >> 4;
    int ry = r / 6, rx = r - ry * 6;
    *(s8b*)&in_l[r * 136 + s * 8] =
        *(const s8b*)&qb[((Y0 + ry) * 130 + X0 + rx) * 128 + s * 8];
  }
  __syncthreads();                                             // S1

  // ---- conv implicit GEMM: M=128 oc, N=32 px, K=1152 ----
  f32x4 acc[4];
#pragma unroll
  for (int a = 0; a < 4; a++) acc[a] = (f32x4){0.f, 0.f, 0.f, 0.f};
  const int pxc = ng * 16 + lm;                 // px 0..31
  const int qy = pxc >> 2, qx = pxc & 3;
#pragma unroll
  for (int t = 0; t < 9; t++) {
    const int dy = t / 3, dx = t - (t / 3) * 3;
#pragma unroll
    for (int kc = 0; kc < 4; kc++) {
      const unsigned short* wp = wb + (t * 4 + kc) * 4096;
      s8b af[4];
#pragma unroll
      for (int mt = 0; mt < 4; mt++)
        af[mt] = *(const s8b*)&wp[((mg * 4 + mt) * 16 + lm) * 32 + kg * 8];
      s8b bf = *(const s8b*)&in_l[((qy + dy) * 6 + qx + dx) * 136 + kc * 32 + kg * 8];
#pragma unroll
      for (int mt = 0; mt < 4; mt++)
        acc[mt] = __builtin_amdgcn_mfma_f32_16x16x32_bf16(af[mt], bf, acc[mt], 0, 0, 0);
    }
  }
  __syncthreads();                                             // S2 (in_l reads done)
#pragma unroll
  for (int mt = 0; mt < 4; mt++)
#pragma unroll
    for (int r = 0; r < 4; r++) {
      int c = (mg * 4 + mt) * 16 + kg * 4 + r;
      qc_l[pxc * 136 + c] = f2bf(acc[mt][r]);
    }
  __syncthreads();                                             // S3

  // ---- q rms (32 px, 8 threads/px) ----
  {
    int px = tid >> 3, t8 = tid & 7;
    const unsigned short* row = &qc_l[px * 136 + t8 * 16];
    s8b v0 = *(const s8b*)row;
    s8b v1 = *(const s8b*)(row + 8);
    float s = 0.f;
#pragma unroll
    for (int e = 0; e < 8; e++) {
      float f0 = b2fs(v0[e]), f1 = b2fs(v1[e]);
      s += f0 * f0 + f1 * f1;
    }
    red_l[px * 8 + t8] = s;
  }
  __syncthreads();                                             // S4
  if (tid < 32) {
    float s = 0.f;
#pragma unroll
    for (int e = 0; e < 8; e++) s += red_l[tid * 8 + e];
    rs_l[tid] = rsqrtf(s * (1.f / 128.f) + EPS_);
  }
  __syncthreads();                                             // S5

  // ---- q proj (A from global wnq) ----
  {
    f32x4 qa[4];
#pragma unroll
    for (int a = 0; a < 4; a++) qa[a] = (f32x4){0.f, 0.f, 0.f, 0.f};
#pragma unroll
    for (int kc = 0; kc < 4; kc++) {
      s8b af[4];
#pragma unroll
      for (int mt = 0; mt < 4; mt++)
        af[mt] = *(const s8b*)&wnq[((mg * 4 + mt) * 16 + lm) * 128 + kc * 32 + kg * 8];
      s8b bf = *(const s8b*)&qc_l[pxc * 136 + kc * 32 + kg * 8];
#pragma unroll
      for (int mt = 0; mt < 4; mt++)
        qa[mt] = __builtin_amdgcn_mfma_f32_16x16x32_bf16(af[mt], bf, qa[mt], 0, 0, 0);
    }
    __syncthreads();                                           // S6 (qc reads done)
    const float rs = rs_l[pxc];
#pragma unroll
    for (int mt = 0; mt < 4; mt++)
#pragma unroll
      for (int r = 0; r < 4; r++) {
        int c = (mg * 4 + mt) * 16 + kg * 4 + r;
        qc_l[pxc * 136 + c] = f2bf(qbias[c] + rs * qa[mt][r]);
      }
  }
  __syncthreads();                                             // S7

  // ---- QK^T: wave = head; B direct from global kpb ----
  const int h = w;
  f32x4 lg[2][4];
  {
    s8b qa[2], kb[4];
#pragma unroll
    for (int mt = 0; mt < 2; mt++)
      qa[mt] = *(const s8b*)&qc_l[(mt * 16 + lm) * 136 + h * 32 + kg * 8];
#pragma unroll
    for (int nt = 0; nt < 4; nt++) {
      int n = nt * 16 + lm;
      int kyL = n >> 3, kxL = n & 7;
      kb[nt] = *(const s8b*)&kpb[((kyb + kyL) * 32 + kxb + kxL) * 128 + h * 32 + kg * 8];
    }
#pragma unroll
    for (int mt = 0; mt < 2; mt++)
#pragma unroll
      for (int nt = 0; nt < 4; nt++)
        lg[mt][nt] = __builtin_amdgcn_mfma_f32_16x16x32_bf16(
            qa[mt], kb[nt], (f32x4){0.f, 0.f, 0.f, 0.f}, 0, 0, 0);
  }
  __syncthreads();                                             // S8 (qc reads done)

  // ---- masked softmax, write P_h into a_l[4][32][72] ----
  {
    const int kyA = lm >> 3, kxq = lm & 7;
    const bool kxv = (unsigned)(kxq - ox) < 7u;
#pragma unroll
    for (int mt = 0; mt < 2; mt++) {
#pragma unroll
      for (int r = 0; r < 4; r++) {
        int j = mt * 16 + kg * 4 + r;                 // q row 0..31
        int oy = ((j >> 4) & 1) ? oy1 : oy0;
        float l[4];
#pragma unroll
        for (int nt = 0; nt < 4; nt++) {
          int ky = 2 * nt + kyA;
          bool valid = kxv && ((unsigned)(ky - oy) < 7u);
          l[nt] = valid ? lg[mt][nt][r] * SCALE_ : -1e30f;
        }
        float mx = fmaxf(fmaxf(l[0], l[1]), fmaxf(l[2], l[3]));
#pragma unroll
        for (int off = 1; off < 16; off <<= 1) mx = fmaxf(mx, __shfl_xor(mx, off, 64));
        float e0 = __expf(l[0] - mx), e1 = __expf(l[1] - mx);
        float e2 = __expf(l[2] - mx), e3 = __expf(l[3] - mx);
        float ss = e0 + e1 + e2 + e3;
#pragma unroll
        for (int off = 1; off < 16; off <<= 1) ss += __shfl_xor(ss, off, 64);
        float inv = 1.f / ss;
        unsigned short* ap = &a_l[(h * 32 + j) * 72];
        ap[lm]      = f2bf(e0 * inv);
        ap[16 + lm] = f2bf(e1 * inv);
        ap[32 + lm] = f2bf(e2 * inv);
        ap[48 + lm] = f2bf(e3 * inv);
      }
    }
  }
  __syncthreads();                                             // S9

  // ---- PV: O = 0.25*sum_h P_h·V ; B direct from global vt; wave = 32-ch band
  f32x4 oacc[2][2];
#pragma unroll
  for (int a = 0; a < 2; a++)
#pragma unroll
    for (int n = 0; n < 2; n++) oacc[a][n] = (f32x4){0.f, 0.f, 0.f, 0.f};
#pragma unroll
  for (int kc = 0; kc < 2; kc++) {
    s8b vb2[2];
#pragma unroll
    for (int nt2 = 0; nt2 < 2; nt2++) {
      int c = w * 32 + nt2 * 16 + lm;
      vb2[nt2] = ld8h(&vt[c * 1024 + (kyb + kc * 4 + kg) * 32 + kxb]);
    }
#pragma unroll
    for (int hh = 0; hh < 4; hh++) {
#pragma unroll
      for (int mt = 0; mt < 2; mt++) {
        s8b pa = *(const s8b*)&a_l[(hh * 32 + mt * 16 + lm) * 72 + kc * 32 + kg * 8];
#pragma unroll
        for (int nt2 = 0; nt2 < 2; nt2++)
          oacc[mt][nt2] = __builtin_amdgcn_mfma_f32_16x16x32_bf16(pa, vb2[nt2], oacc[mt][nt2], 0, 0, 0);
      }
    }
  }
  __syncthreads();                                             // S10 (a_l reads done)

  // ---- transposed output o_l[c][q], then global ----
#pragma unroll
  for (int mt = 0; mt < 2; mt++)
#pragma unroll
    for (int nt2 = 0; nt2 < 2; nt2++)
#pragma unroll
      for (int r = 0; r < 4; r++)
        o_l[(w * 32 + nt2 * 16 + lm) * 36 + mt * 16 + kg * 4 + r] = 0.25f * oacc[mt][nt2][r];
  __syncthreads();                                             // S11
  for (int i = tid; i < 1024; i += 256) {
    int c = i >> 3, qyo = i & 7;
    float4 v = *(const float4*)&o_l[c * 36 + qyo * 4];
    *(float4*)&out[c * 16384 + (Y0 + qyo) * 128 + X0] = v;
  }
}

// ---------------------------------------------------------------------------
extern "C" void kernel_launch(void* const* d_in, const int* in_sizes, int n_in,
                              void* d_out, int out_size, void* d_ws, size_t ws_size,
                              hipStream_t stream) {
  const float* q_in    = (const float*)d_in[0];
  const float* k_in    = (const float*)d_in[1];
  const float* v_in    = (const float*)d_in[2];
  const float* conv_w  = (const float*)d_in[3];
  const float* normq_w = (const float*)d_in[4];
  const float* normk_w = (const float*)d_in[5];
  const float* qproj_w = (const float*)d_in[6];
  const float* qproj_b = (const float*)d_in[7];
  const float* kproj_w = (const float*)d_in[8];
  const float* kproj_b = (const float*)d_in[9];
  float* out = (float*)d_out;

  char* ws = (char*)d_ws;
  unsigned short* qb  = (unsigned short*)(ws);             // [130][130][128] bf16
  unsigned short* kpb = (unsigned short*)(ws + 4326400);   // [1024][128] bf16
  unsigned short* vt  = (unsigned short*)(ws + 4588544);   // [128][1024] bf16
  unsigned short* wb  = (unsigned short*)(ws + 4850688);   // [9][4][128][32] bf16
  unsigned short* wnq = (unsigned short*)(ws + 5145600);   // [128][128] bf16

  prep_k<<<dim3(985), 256, 0, stream>>>(q_in, k_in, v_in, conv_w, normq_w, normk_w,
                                        qproj_w, kproj_w, kproj_b,
                                        qb, kpb, vt, wb, wnq);
  fused_k<<<dim3(512), 256, 0, stream>>>(qb, kpb, vt, wb, wnq, qproj_b, out);
}

// Round 9
// 119.756 us; speedup vs baseline: 1.0156x; 1.0156x over previous
//
#include <hip/hip_runtime.h>

#define EPS_ 1.1920928955078125e-07f
#define SCALE_ 0.17677669529663687f   // 1/sqrt(32)

typedef __attribute__((ext_vector_type(8))) short s8b;     // 8 bf16 (16B)
typedef __attribute__((ext_vector_type(4))) float f32x4;   // MFMA acc

static __device__ __forceinline__ unsigned short f2bf(float f) {
  unsigned int u = __float_as_uint(f);
  unsigned int r = (u + 0x7fffu + ((u >> 16) & 1u)) >> 16;   // RNE
  return (unsigned short)r;
}
static __device__ __forceinline__ float b2fs(short h) {
  return __uint_as_float(((unsigned int)(unsigned short)h) << 16);
}
static __device__ __forceinline__ int S_(int c) {        // NATTEN window start (cell grid)
  return (c < 3) ? 0 : ((c > 28) ? 25 : (c - 3));
}
// 16B of bf16 from a 4B-aligned pointer (4 dword loads)
static __device__ __forceinline__ s8b ld8h(const unsigned short* p) {
  const unsigned int* u = (const unsigned int*)p;
  union { unsigned int u4[4]; s8b v; } r;
  r.u4[0] = u[0]; r.u4[1] = u[1]; r.u4[2] = u[2]; r.u4[3] = u[3];
  return r.v;
}

// ---------------------------------------------------------------------------
// prep (grid 985):
//  [0,256)   q fp32 NCHW -> bf16 NHWC padded qb [130][130][128]
//  [256,265) zero qb halo border
//  [265,281) k-side: rms + kproj MFMA -> kpb [1024][128] bf16 NHWC (64 px/blk)
//  [281,345) v fp32 -> vt bf16 [128][1024] (same layout, cast only)
//  [345,985) weight packs: wb [9][4][128oc][32ic], wnq [128][128]
// ---------------------------------------------------------------------------
__global__ __launch_bounds__(256) void prep_k(
    const float* __restrict__ q_in, const float* __restrict__ k_in,
    const float* __restrict__ v_in, const float* __restrict__ conv_w,
    const float* __restrict__ normq_w, const float* __restrict__ normk_w,
    const float* __restrict__ qproj_w, const float* __restrict__ kproj_w,
    const float* __restrict__ kbias,
    unsigned short* __restrict__ qb, unsigned short* __restrict__ kpb,
    unsigned short* __restrict__ vt, unsigned short* __restrict__ wb,
    unsigned short* __restrict__ wnq) {
  __shared__ __align__(16) char smem[53504];
  unsigned short* t_l = (unsigned short*)smem;             // [64][136]
  unsigned short* x_l = (unsigned short*)smem;             // [64][136] (k-proj)
  unsigned short* wnk_l = (unsigned short*)(smem + 17408); // [128][136]
  float* red_l = (float*)(smem + 52224);                   // [256]
  float* rs_l  = (float*)(smem + 53248);                   // [64]
  const int b = blockIdx.x, tid = threadIdx.x;
  const int w = tid >> 6, lane = tid & 63;
  const int lm = lane & 15, kg = lane >> 4;

  if (b < 256) {
    const int px0 = b * 64;
    for (int i = tid; i < 2048; i += 256) {
      int c = i >> 4, f = i & 15;
      float4 v = *(const float4*)&q_in[c * 16384 + px0 + f * 4];
      t_l[(f * 4 + 0) * 136 + c] = f2bf(v.x);
      t_l[(f * 4 + 1) * 136 + c] = f2bf(v.y);
      t_l[(f * 4 + 2) * 136 + c] = f2bf(v.z);
      t_l[(f * 4 + 3) * 136 + c] = f2bf(v.w);
    }
    __syncthreads();
    for (int i = tid; i < 1024; i += 256) {
      int p = i >> 4, s = i & 15;
      int px = px0 + p;
      int opx = px + 2 * (px >> 7) + 131;   // (y+1)*130 + (x+1)
      *(s8b*)&qb[opx * 128 + s * 8] = *(const s8b*)&t_l[p * 136 + s * 8];
    }
  } else if (b < 265) {
    int gid = (b - 256) * 256 + tid;   // 2304 threads
    s8b z = {0, 0, 0, 0, 0, 0, 0, 0};
    for (int j = gid; j < 2080; j += 2304) {
      *(s8b*)&qb[j * 8] = z;
      *(s8b*)&qb[129 * 130 * 128 + j * 8] = z;
    }
    for (int j = gid; j < 2048; j += 2304) {
      int r = (j >> 4) + 1, s = j & 15;
      *(s8b*)&qb[(r * 130) * 128 + s * 8] = z;
      *(s8b*)&qb[(r * 130 + 129) * 128 + s * 8] = z;
    }
  } else if (b < 281) {
    // ------- k-side rms + proj, 64 px -------
    const int px0 = (b - 265) * 64;
    for (int i = tid; i < 2048; i += 256) {
      int c = i >> 4, f = i & 15;
      float4 v = *(const float4*)&k_in[c * 1024 + px0 + f * 4];
      x_l[(f * 4 + 0) * 136 + c] = f2bf(v.x);
      x_l[(f * 4 + 1) * 136 + c] = f2bf(v.y);
      x_l[(f * 4 + 2) * 136 + c] = f2bf(v.z);
      x_l[(f * 4 + 3) * 136 + c] = f2bf(v.w);
    }
    for (int i = tid; i < 16384; i += 256) {
      int o = i >> 7, c = i & 127;
      wnk_l[o * 136 + c] = f2bf(kproj_w[i] * normk_w[c]);
    }
    __syncthreads();
    {
      int px = tid >> 2, t4 = tid & 3;
      float ssum = 0.f;
#pragma unroll
      for (int j = 0; j < 4; j++) {
        s8b v = *(const s8b*)&x_l[px * 136 + t4 * 32 + j * 8];
#pragma unroll
        for (int e = 0; e < 8; e++) { float f = b2fs(v[e]); ssum += f * f; }
      }
      red_l[px * 4 + t4] = ssum;
    }
    __syncthreads();
    if (tid < 64)
      rs_l[tid] = rsqrtf((red_l[4 * tid] + red_l[4 * tid + 1] + red_l[4 * tid + 2] +
                          red_l[4 * tid + 3]) * (1.f / 128.f) + EPS_);
    __syncthreads();
    f32x4 acc[2][4];
#pragma unroll
    for (int a = 0; a < 2; a++)
#pragma unroll
      for (int n = 0; n < 4; n++) acc[a][n] = (f32x4){0.f, 0.f, 0.f, 0.f};
#pragma unroll
    for (int kc = 0; kc < 4; kc++) {
      s8b a0 = *(const s8b*)&wnk_l[(2 * w * 16 + lm) * 136 + kc * 32 + kg * 8];
      s8b a1 = *(const s8b*)&wnk_l[((2 * w + 1) * 16 + lm) * 136 + kc * 32 + kg * 8];
#pragma unroll
      for (int nt = 0; nt < 4; nt++) {
        s8b bf = *(const s8b*)&x_l[(nt * 16 + lm) * 136 + kc * 32 + kg * 8];
        acc[0][nt] = __builtin_amdgcn_mfma_f32_16x16x32_bf16(a0, bf, acc[0][nt], 0, 0, 0);
        acc[1][nt] = __builtin_amdgcn_mfma_f32_16x16x32_bf16(a1, bf, acc[1][nt], 0, 0, 0);
      }
    }
    __syncthreads();
#pragma unroll
    for (int mi = 0; mi < 2; mi++)
#pragma unroll
      for (int nt = 0; nt < 4; nt++)
#pragma unroll
        for (int r = 0; r < 4; r++) {
          int px = nt * 16 + lm, c = (2 * w + mi) * 16 + kg * 4 + r;
          x_l[px * 136 + c] = f2bf(kbias[c] + rs_l[px] * acc[mi][nt][r]);
        }
    __syncthreads();
    for (int i = tid; i < 1024; i += 256) {
      int px = i >> 4, s = i & 15;
      *(s8b*)&kpb[(px0 + px) * 128 + s * 8] = *(const s8b*)&x_l[px * 136 + s * 8];
    }
  } else if (b < 345) {
    // ------- vt: bf16 cast of v (layout unchanged) -------
    int base = (b - 281) * 2048 + tid * 8;
    float4 v0 = *(const float4*)&v_in[base];
    float4 v1 = *(const float4*)&v_in[base + 4];
    s8b o;
    o[0] = (short)f2bf(v0.x); o[1] = (short)f2bf(v0.y);
    o[2] = (short)f2bf(v0.z); o[3] = (short)f2bf(v0.w);
    o[4] = (short)f2bf(v1.x); o[5] = (short)f2bf(v1.y);
    o[6] = (short)f2bf(v1.z); o[7] = (short)f2bf(v1.w);
    *(s8b*)&vt[base] = o;
  } else {
    int idx = (b - 345) * 256 + tid;   // < 163840
    if (idx < 147456) {
      int i32 = idx & 31, r = idx >> 5;
      int oc = r & 127, r2 = r >> 7;
      int kc = r2 & 3, t = r2 >> 2;
      wb[idx] = f2bf(conv_w[oc * 1152 + (kc * 32 + i32) * 9 + t]);
    } else {
      int j = idx - 147456;
      wnq[j] = f2bf(qproj_w[j] * normq_w[j & 127]);
    }
  }
}

// ---------------------------------------------------------------------------
// fused (grid 512, 256 thr = 4 waves): per 8y x 4x output tile.
// Conv halo staged in LDS; all other operands (weights, K, V) from L2-hot
// global. launch_bounds(256,2): VGPR cap 256 — R8's (256,4) forced 40 VGPRs
// and spilled ~16 dwords/thread to scratch (WRITE_SIZE 2x output).
// LDS (19584B): R0 @0 (18432): in_l[60][136] -> qc_l[32][136] -> a_l[4][32][72]
//               -> o_l[128][36] f32 ; red @18432 [256] ; rs @19456 [32]
// ---------------------------------------------------------------------------
__global__ __launch_bounds__(256, 2) void fused_k(
    const unsigned short* __restrict__ qb, const unsigned short* __restrict__ kpb,
    const unsigned short* __restrict__ vt, const unsigned short* __restrict__ wb,
    const unsigned short* __restrict__ wnq, const float* __restrict__ qbias,
    float* __restrict__ out) {
  __shared__ __align__(16) char smem[19584];
  unsigned short* in_l = (unsigned short*)smem;
  unsigned short* qc_l = (unsigned short*)smem;
  unsigned short* a_l  = (unsigned short*)smem;
  float* o_l   = (float*)smem;
  float* red_l = (float*)(smem + 18432);
  float* rs_l  = (float*)(smem + 19456);

  const int tid = threadIdx.x;                 // 0..255
  const int TY = blockIdx.x >> 5, TX = blockIdx.x & 31;
  const int Y0 = TY * 8, X0 = TX * 4;
  const int w = tid >> 6, lane = tid & 63;
  const int lm = lane & 15, kg = lane >> 4;
  const int mg = w & 1, ng = w >> 1;           // conv/proj: 4 m-tiles, 1 n-tile

  const int sy0 = S_(2 * TY), sy1 = S_(2 * TY + 1);
  const int sx  = S_(TX);
  const int kyb = min(sy0, 24);
  const int kxb = sx & ~1;                     // even -> 4B-aligned V rows
  const int oy0 = sy0 - kyb, oy1 = sy1 - kyb;
  const int ox  = sx - kxb;

  // ---- stage conv halo [60][136] from padded qb ----
  for (int i = tid; i < 960; i += 256) {
    int s = i & 15, r = i >> 4;
    int ry = r / 6, rx = r - ry * 6;
    *(s8b*)&in_l[r * 136 + s * 8] =
        *(const s8b*)&qb[((Y0 + ry) * 130 + X0 + rx) * 128 + s * 8];
  }
  __syncthreads();                                             // S1

  // ---- conv implicit GEMM: M=128 oc, N=32 px, K=1152 ----
  f32x4 acc[4];
#pragma unroll
  for (int a = 0; a < 4; a++) acc[a] = (f32x4){0.f, 0.f, 0.f, 0.f};
  const int pxc = ng * 16 + lm;                 // px 0..31
  const int qy = pxc >> 2, qx = pxc & 3;
#pragma unroll
  for (int t = 0; t < 9; t++) {
    const int dy = t / 3, dx = t - (t / 3) * 3;
#pragma unroll
    for (int kc = 0; kc < 4; kc++) {
      const unsigned short* wp = wb + (t * 4 + kc) * 4096;
      s8b af[4];
#pragma unroll
      for (int mt = 0; mt < 4; mt++)
        af[mt] = *(const s8b*)&wp[((mg * 4 + mt) * 16 + lm) * 32 + kg * 8];
      s8b bf = *(const s8b*)&in_l[((qy + dy) * 6 + qx + dx) * 136 + kc * 32 + kg * 8];
#pragma unroll
      for (int mt = 0; mt < 4; mt++)
        acc[mt] = __builtin_amdgcn_mfma_f32_16x16x32_bf16(af[mt], bf, acc[mt], 0, 0, 0);
    }
  }
  __syncthreads();                                             // S2 (in_l reads done)
#pragma unroll
  for (int mt = 0; mt < 4; mt++)
#pragma unroll
    for (int r = 0; r < 4; r++) {
      int c = (mg * 4 + mt) * 16 + kg * 4 + r;
      qc_l[pxc * 136 + c] = f2bf(acc[mt][r]);
    }
  __syncthreads();                                             // S3

  // ---- q rms (32 px, 8 threads/px) ----
  {
    int px = tid >> 3, t8 = tid & 7;
    const unsigned short* row = &qc_l[px * 136 + t8 * 16];
    s8b v0 = *(const s8b*)row;
    s8b v1 = *(const s8b*)(row + 8);
    float s = 0.f;
#pragma unroll
    for (int e = 0; e < 8; e++) {
      float f0 = b2fs(v0[e]), f1 = b2fs(v1[e]);
      s += f0 * f0 + f1 * f1;
    }
    red_l[px * 8 + t8] = s;
  }
  __syncthreads();                                             // S4
  if (tid < 32) {
    float s = 0.f;
#pragma unroll
    for (int e = 0; e < 8; e++) s += red_l[tid * 8 + e];
    rs_l[tid] = rsqrtf(s * (1.f / 128.f) + EPS_);
  }
  __syncthreads();                                             // S5

  // ---- q proj (A from global wnq) ----
  {
    f32x4 qa[4];
#pragma unroll
    for (int a = 0; a < 4; a++) qa[a] = (f32x4){0.f, 0.f, 0.f, 0.f};
#pragma unroll
    for (int kc = 0; kc < 4; kc++) {
      s8b af[4];
#pragma unroll
      for (int mt = 0; mt < 4; mt++)
        af[mt] = *(const s8b*)&wnq[((mg * 4 + mt) * 16 + lm) * 128 + kc * 32 + kg * 8];
      s8b bf = *(const s8b*)&qc_l[pxc * 136 + kc * 32 + kg * 8];
#pragma unroll
      for (int mt = 0; mt < 4; mt++)
        qa[mt] = __builtin_amdgcn_mfma_f32_16x16x32_bf16(af[mt], bf, qa[mt], 0, 0, 0);
    }
    __syncthreads();                                           // S6 (qc reads done)
    const float rs = rs_l[pxc];
#pragma unroll
    for (int mt = 0; mt < 4; mt++)
#pragma unroll
      for (int r = 0; r < 4; r++) {
        int c = (mg * 4 + mt) * 16 + kg * 4 + r;
        qc_l[pxc * 136 + c] = f2bf(qbias[c] + rs * qa[mt][r]);
      }
  }
  __syncthreads();                                             // S7

  // ---- QK^T: wave = head; B direct from global kpb ----
  const int h = w;
  f32x4 lg[2][4];
  {
    s8b qa[2], kb[4];
#pragma unroll
    for (int mt = 0; mt < 2; mt++)
      qa[mt] = *(const s8b*)&qc_l[(mt * 16 + lm) * 136 + h * 32 + kg * 8];
#pragma unroll
    for (int nt = 0; nt < 4; nt++) {
      int n = nt * 16 + lm;
      int kyL = n >> 3, kxL = n & 7;
      kb[nt] = *(const s8b*)&kpb[((kyb + kyL) * 32 + kxb + kxL) * 128 + h * 32 + kg * 8];
    }
#pragma unroll
    for (int mt = 0; mt < 2; mt++)
#pragma unroll
      for (int nt = 0; nt < 4; nt++)
        lg[mt][nt] = __builtin_amdgcn_mfma_f32_16x16x32_bf16(
            qa[mt], kb[nt], (f32x4){0.f, 0.f, 0.f, 0.f}, 0, 0, 0);
  }
  __syncthreads();                                             // S8 (qc reads done)

  // ---- masked softmax, write P_h into a_l[4][32][72] ----
  {
    const int kyA = lm >> 3, kxq = lm & 7;
    const bool kxv = (unsigned)(kxq - ox) < 7u;
#pragma unroll
    for (int mt = 0; mt < 2; mt++) {
#pragma unroll
      for (int r = 0; r < 4; r++) {
        int j = mt * 16 + kg * 4 + r;                 // q row 0..31
        int oy = ((j >> 4) & 1) ? oy1 : oy0;
        float l[4];
#pragma unroll
        for (int nt = 0; nt < 4; nt++) {
          int ky = 2 * nt + kyA;
          bool valid = kxv && ((unsigned)(ky - oy) < 7u);
          l[nt] = valid ? lg[mt][nt][r] * SCALE_ : -1e30f;
        }
        float mx = fmaxf(fmaxf(l[0], l[1]), fmaxf(l[2], l[3]));
#pragma unroll
        for (int off = 1; off < 16; off <<= 1) mx = fmaxf(mx, __shfl_xor(mx, off, 64));
        float e0 = __expf(l[0] - mx), e1 = __expf(l[1] - mx);
        float e2 = __expf(l[2] - mx), e3 = __expf(l[3] - mx);
        float ss = e0 + e1 + e2 + e3;
#pragma unroll
        for (int off = 1; off < 16; off <<= 1) ss += __shfl_xor(ss, off, 64);
        float inv = 1.f / ss;
        unsigned short* ap = &a_l[(h * 32 + j) * 72];
        ap[lm]      = f2bf(e0 * inv);
        ap[16 + lm] = f2bf(e1 * inv);
        ap[32 + lm] = f2bf(e2 * inv);
        ap[48 + lm] = f2bf(e3 * inv);
      }
    }
  }
  __syncthreads();                                             // S9

  // ---- PV: O = 0.25*sum_h P_h·V ; B direct from global vt; wave = 32-ch band
  f32x4 oacc[2][2];
#pragma unroll
  for (int a = 0; a < 2; a++)
#pragma unroll
    for (int n = 0; n < 2; n++) oacc[a][n] = (f32x4){0.f, 0.f, 0.f, 0.f};
#pragma unroll
  for (int kc = 0; kc < 2; kc++) {
    s8b vb2[2];
#pragma unroll
    for (int nt2 = 0; nt2 < 2; nt2++) {
      int c = w * 32 + nt2 * 16 + lm;
      vb2[nt2] = ld8h(&vt[c * 1024 + (kyb + kc * 4 + kg) * 32 + kxb]);
    }
#pragma unroll
    for (int hh = 0; hh < 4; hh++) {
#pragma unroll
      for (int mt = 0; mt < 2; mt++) {
        s8b pa = *(const s8b*)&a_l[(hh * 32 + mt * 16 + lm) * 72 + kc * 32 + kg * 8];
#pragma unroll
        for (int nt2 = 0; nt2 < 2; nt2++)
          oacc[mt][nt2] = __builtin_amdgcn_mfma_f32_16x16x32_bf16(pa, vb2[nt2], oacc[mt][nt2], 0, 0, 0);
      }
    }
  }
  __syncthreads();                                             // S10 (a_l reads done)

  // ---- transposed output o_l[c][q], then global ----
#pragma unroll
  for (int mt = 0; mt < 2; mt++)
#pragma unroll
    for (int nt2 = 0; nt2 < 2; nt2++)
#pragma unroll
      for (int r = 0; r < 4; r++)
        o_l[(w * 32 + nt2 * 16 + lm) * 36 + mt * 16 + kg * 4 + r] = 0.25f * oacc[mt][nt2][r];
  __syncthreads();                                             // S11
  for (int i = tid; i < 1024; i += 256) {
    int c = i >> 3, qyo = i & 7;
    float4 v = *(const float4*)&o_l[c * 36 + qyo * 4];
    *(float4*)&out[c * 16384 + (Y0 + qyo) * 128 + X0] = v;
  }
}

// ---------------------------------------------------------------------------
extern "C" void kernel_launch(void* const* d_in, const int* in_sizes, int n_in,
                              void* d_out, int out_size, void* d_ws, size_t ws_size,
                              hipStream_t stream) {
  const float* q_in    = (const float*)d_in[0];
  const float* k_in    = (const float*)d_in[1];
  const float* v_in    = (const float*)d_in[2];
  const float* conv_w  = (const float*)d_in[3];
  const float* normq_w = (const float*)d_in[4];
  const float* normk_w = (const float*)d_in[5];
  const float* qproj_w = (const float*)d_in[6];
  const float* qproj_b = (const float*)d_in[7];
  const float* kproj_w = (const float*)d_in[8];
  const float* kproj_b = (const float*)d_in[9];
  float* out = (float*)d_out;

  char* ws = (char*)d_ws;
  unsigned short* qb  = (unsigned short*)(ws);             // [130][130][128] bf16
  unsigned short* kpb = (unsigned short*)(ws + 4326400);   // [1024][128] bf16
  unsigned short* vt  = (unsigned short*)(ws + 4588544);   // [128][1024] bf16
  unsigned short* wb  = (unsigned short*)(ws + 4850688);   // [9][4][128][32] bf16
  unsigned short* wnq = (unsigned short*)(ws + 5145600);   // [128][128] bf16

  prep_k<<<dim3(985), 256, 0, stream>>>(q_in, k_in, v_in, conv_w, normq_w, normk_w,
                                        qproj_w, kproj_w, kproj_b,
                                        qb, kpb, vt, wb, wnq);
  fused_k<<<dim3(512), 256, 0, stream>>>(qb, kpb, vt, wb, wnq, qproj_b, out);
}